// Round 8
// baseline (57.619 us; speedup 1.0000x reference)
//
#include <hip/hip_runtime.h>
#include <hip/hip_bf16.h>

typedef __bf16 bf16x8 __attribute__((ext_vector_type(8)));
typedef float  f32x16 __attribute__((ext_vector_type(16)));

static constexpr int NB = 8;
static constexpr int S  = 2048;
static constexpr int T  = 2048;
static constexpr int D  = 128;

// ws layout: wsrc[16384 rows][16 uint4], wtar[16384 rows][16 uint4]  (8 MB)
// Each row: 128 bf16 (normalized, mask-folded), slot q stored at (q ^ (row&7))
// == the exact LDS image the GEMM wants (global_load_lds copies linearly).

__device__ __forceinline__ void g2l(const uint4* g, uint4* l) {
    __builtin_amdgcn_global_load_lds((const __attribute__((address_space(1))) void*)g,
                                     (__attribute__((address_space(3))) void*)l, 16, 0, 0);
}

// ---------------- pass 1: normalize + mask-zero + bf16 + swizzled image ----------------
// Full chip: 256 blocks x 512 threads, 4 threads per row (32 floats each).
__global__ __launch_bounds__(512, 2)
void prep(const float* __restrict__ src, const float* __restrict__ tar,
          const int* __restrict__ ms, const int* __restrict__ mt,
          uint4* __restrict__ ws)
{
    const int tid  = threadIdx.x;
    const int qid  = blockIdx.x * 512 + tid;    // quarter-row id, 0..131071
    const int row  = qid >> 2;                  // 0..32767  (src rows then tar rows)
    const int q    = qid & 3;
    const bool isT = row >= NB * S;
    const int  r   = isT ? row - NB * S : row;  // 0..16383 within src/tar
    const float* p = (isT ? tar : src) + (size_t)r * D + q * 32;
    const int   mk = (isT ? mt : ms)[r];
    uint4*      wp = ws + (size_t)row * 16;

    float4 v[8];
    float ss = 0.f;
    if (mk) {
        #pragma unroll
        for (int j = 0; j < 8; ++j) {
            v[j] = ((const float4*)p)[j];
            ss += v[j].x * v[j].x + v[j].y * v[j].y + v[j].z * v[j].z + v[j].w * v[j].w;
        }
    } else {
        #pragma unroll
        for (int j = 0; j < 8; ++j) v[j] = float4{0.f, 0.f, 0.f, 0.f};
    }
    ss += __shfl_xor(ss, 1);                    // 4-lane group reduce (lanes of one row)
    ss += __shfl_xor(ss, 2);
    const float sc = mk ? (1.0f / fmaxf(sqrtf(ss), 1e-12f)) : 0.0f;

    #pragma unroll
    for (int i = 0; i < 4; ++i) {
        const float4 u0 = v[2 * i], u1 = v[2 * i + 1];
        bf16x8 t;
        t[0] = (__bf16)(u0.x * sc); t[1] = (__bf16)(u0.y * sc);
        t[2] = (__bf16)(u0.z * sc); t[3] = (__bf16)(u0.w * sc);
        t[4] = (__bf16)(u1.x * sc); t[5] = (__bf16)(u1.y * sc);
        t[6] = (__bf16)(u1.z * sc); t[7] = (__bf16)(u1.w * sc);
        wp[(q * 4 + i) ^ (r & 7)] = __builtin_bit_cast(uint4, t);
    }
}

// ---------------- pass 2: tiled GEMM (32x32x16 MFMA), 2 tiles per block ----------------
// D = src_frag * tar_frag: C/D col = t = lane&31 -> per-reg store covers
// 2 s-rows x 32 consecutive t floats = two aligned 128B full lines.
__global__ __launch_bounds__(512, 2)
void gemm(const uint4* __restrict__ ws, float* __restrict__ out)
{
    __shared__ uint4 ldsS[256 * 16];   // src panel (A operand, 256 s-rows)
    __shared__ uint4 ldsT[256 * 16];   // tar panel (B operand, 256 t-rows)

    const uint4* wsrc = ws;
    const uint4* wtar = ws + (size_t)NB * S * 16;

    const int p   = blockIdx.x;        // 0..255 ; round-robin => b == XCD id
    const int b   = p & 7;
    const int k   = p >> 3;            // 0..31
    const int ts  = k >> 2;            // 0..7
    const int tt0 = (k & 3) * 2;       // {0,2,4,6}

    const int tid  = threadIdx.x;
    const int lane = tid & 63;
    const int w    = tid >> 6;
    const int wt   = w >> 1;           // 0..3  t-strip (64 t-rows)
    const int wsp  = w & 1;            // 0..1  s-strip (128 s-rows)
    const int l31  = lane & 31;
    const int hi   = lane >> 5;        // 0..1  (selects k-half and s-row offset)

    const uint4* gs  = wsrc + ((size_t)(b * S + ts * 256)) * 16;
    const uint4* gt0 = wtar + ((size_t)(b * T + tt0 * 256)) * 16;
    const uint4* gt1 = gt0 + 256 * 16;

    // stage: both panels (linear copy of pre-swizzled image)
    #pragma unroll
    for (int i = 0; i < 8; ++i) {
        const int idx = i * 512 + tid;
        g2l(gs + idx,  &ldsS[i * 512 + w * 64]);
        g2l(gt0 + idx, &ldsT[i * 512 + w * 64]);
    }
    __syncthreads();

    f32x16 acc[4][2];

    #pragma unroll
    for (int tile = 0; tile < 2; ++tile) {
        #pragma unroll
        for (int fs = 0; fs < 4; ++fs)
            #pragma unroll
            for (int ft = 0; ft < 2; ++ft)
                #pragma unroll
                for (int r = 0; r < 16; ++r)
                    acc[fs][ft][r] = 0.f;

        #pragma unroll
        for (int ks = 0; ks < 8; ++ks) {          // K = 8 * 16
            bf16x8 a[4], bt[2];
            #pragma unroll
            for (int fs = 0; fs < 4; ++fs) {
                const int rl = wsp * 128 + fs * 32 + l31;
                a[fs] = __builtin_bit_cast(bf16x8, ldsS[rl * 16 + ((ks * 2 + hi) ^ (rl & 7))]);
            }
            #pragma unroll
            for (int ft = 0; ft < 2; ++ft) {
                const int rl = wt * 64 + ft * 32 + l31;
                bt[ft] = __builtin_bit_cast(bf16x8, ldsT[rl * 16 + ((ks * 2 + hi) ^ (rl & 7))]);
            }
            #pragma unroll
            for (int fs = 0; fs < 4; ++fs)
                #pragma unroll
                for (int ft = 0; ft < 2; ++ft)
                    acc[fs][ft] = __builtin_amdgcn_mfma_f32_32x32x16_bf16(a[fs], bt[ft], acc[fs][ft], 0, 0, 0);
        }

        if (tile == 0) {
            __syncthreads();                       // all waves done reading ldsT
            #pragma unroll
            for (int i = 0; i < 8; ++i)            // prefetch next tar panel
                g2l(gt1 + i * 512 + tid, &ldsT[i * 512 + w * 64]);
            asm volatile("s_waitcnt vmcnt(0)" ::: "memory");  // only these 16 loads outstanding
            __builtin_amdgcn_s_barrier();
            __builtin_amdgcn_sched_barrier(0);
        }

        // epilogue: ReLU + full-line stores (norms & masks folded in prep)
        const int ttc = (tile == 0) ? tt0 : tt0 + 1;
        const float* dummy;
        #pragma unroll
        for (int fs = 0; fs < 4; ++fs) {
            const int s0 = wsp * 128 + fs * 32 + 4 * hi;   // + srow(reg)
            float* pb = out + ((size_t)(b * S + ts * 256 + s0)) * T + ttc * 256 + wt * 64 + l31;
            #pragma unroll
            for (int ft = 0; ft < 2; ++ft) {
                #pragma unroll
                for (int r = 0; r < 16; ++r) {
                    const int srow = (r & 3) + 8 * (r >> 2);   // 0..27
                    pb[(size_t)srow * T + ft * 32] = fmaxf(acc[fs][ft][r], 0.f);
                }
            }
        }
        (void)dummy;
    }
}

extern "C" void kernel_launch(void* const* d_in, const int* in_sizes, int n_in,
                              void* d_out, int out_size, void* d_ws, size_t ws_size,
                              hipStream_t stream) {
    const float* src    = (const float*)d_in[0];
    const float* tar    = (const float*)d_in[1];
    const int*   mask_s = (const int*)d_in[2];
    const int*   mask_t = (const int*)d_in[3];
    float*       out    = (float*)d_out;
    uint4*       ws     = (uint4*)d_ws;

    hipLaunchKernelGGL(prep, dim3(256), dim3(512), 0, stream, src, tar, mask_s, mask_t, ws);
    hipLaunchKernelGGL(gemm, dim3(256), dim3(512), 0, stream, ws, out);
}

// Round 9
// 35.925 us; speedup vs baseline: 1.6039x; 1.6039x over previous
//
#include <hip/hip_runtime.h>
#include <hip/hip_bf16.h>

typedef __bf16 bf16x8 __attribute__((ext_vector_type(8)));
typedef float  f32x4  __attribute__((ext_vector_type(4)));

static constexpr int NB = 8;
static constexpr int S  = 2048;
static constexpr int T  = 2048;
static constexpr int D  = 128;

// ws layout: wsrc[16384 rows][16 uint4], wtar[16384 rows][16 uint4]  (8 MB)
// Each row: 128 bf16 (normalized, mask-folded), slot q stored at (q ^ (row&7))
// == the exact LDS image the GEMM wants (global_load_lds copies linearly).

__device__ __forceinline__ void g2l(const uint4* g, uint4* l) {
    __builtin_amdgcn_global_load_lds((const __attribute__((address_space(1))) void*)g,
                                     (__attribute__((address_space(3))) void*)l, 16, 0, 0);
}

// ---------------- pass 1: normalize + mask-zero + bf16 + swizzled image ----------------
// Full chip: 256 blocks x 512 threads, 4 threads per row (32 floats each).
__global__ __launch_bounds__(512, 2)
void prep(const float* __restrict__ src, const float* __restrict__ tar,
          const int* __restrict__ ms, const int* __restrict__ mt,
          uint4* __restrict__ ws)
{
    const int tid  = threadIdx.x;
    const int qid  = blockIdx.x * 512 + tid;    // quarter-row id, 0..131071
    const int row  = qid >> 2;                  // 0..32767  (src rows then tar rows)
    const int q    = qid & 3;
    const bool isT = row >= NB * S;
    const int  r   = isT ? row - NB * S : row;  // 0..16383 within src/tar
    const float* p = (isT ? tar : src) + (size_t)r * D + q * 32;
    const int   mk = (isT ? mt : ms)[r];
    uint4*      wp = ws + (size_t)row * 16;

    float4 v[8];
    float ss = 0.f;
    if (mk) {
        #pragma unroll
        for (int j = 0; j < 8; ++j) {
            v[j] = ((const float4*)p)[j];
            ss += v[j].x * v[j].x + v[j].y * v[j].y + v[j].z * v[j].z + v[j].w * v[j].w;
        }
    } else {
        #pragma unroll
        for (int j = 0; j < 8; ++j) v[j] = float4{0.f, 0.f, 0.f, 0.f};
    }
    ss += __shfl_xor(ss, 1);                    // 4-lane group reduce (lanes of one row)
    ss += __shfl_xor(ss, 2);
    const float sc = mk ? (1.0f / fmaxf(sqrtf(ss), 1e-12f)) : 0.0f;

    #pragma unroll
    for (int i = 0; i < 4; ++i) {
        const float4 u0 = v[2 * i], u1 = v[2 * i + 1];
        bf16x8 t;
        t[0] = (__bf16)(u0.x * sc); t[1] = (__bf16)(u0.y * sc);
        t[2] = (__bf16)(u0.z * sc); t[3] = (__bf16)(u0.w * sc);
        t[4] = (__bf16)(u1.x * sc); t[5] = (__bf16)(u1.y * sc);
        t[6] = (__bf16)(u1.z * sc); t[7] = (__bf16)(u1.w * sc);
        wp[(q * 4 + i) ^ (r & 7)] = __builtin_bit_cast(uint4, t);
    }
}

// ---------------- pass 2: tiled GEMM, 128s x 256t per block, 2 blocks/CU ----------------
// 1024 blocks: 4 sequential blocks per CU overlap each other's stage/compute/
// store-drain phases. Per block: stage S panel (128 rows) + T panel (128 rows),
// compute 128x128 tile, prefetch next T panel, compute second tile.
__global__ __launch_bounds__(512, 4)
void gemm(const uint4* __restrict__ ws, float* __restrict__ out)
{
    __shared__ uint4 ldsS[128 * 16];   // 32 KB  src panel (B operand, 128 s-rows)
    __shared__ uint4 ldsT[128 * 16];   // 32 KB  tar panel (A operand, 128 t-rows)

    const uint4* wsrc = ws;
    const uint4* wtar = ws + (size_t)NB * S * 16;

    const int p  = blockIdx.x;         // 0..1023 ; round-robin => b == XCD id
    const int b  = p & 7;
    const int q  = p >> 3;             // 0..127
    const int ts = q >> 3;             // 0..15  source tile (128 rows)
    const int tp = q & 7;              // 0..7   target pair (2 x 128 rows)

    const int tid  = threadIdx.x;
    const int lane = tid & 63;
    const int w    = tid >> 6;
    const int wt   = w & 1;            // 0..1  t-half (64 t-rows)
    const int wsp  = w >> 1;           // 0..3  s-quarter (32 s-rows)
    const int r16  = lane & 15;
    const int kg   = lane >> 4;        // 0..3
    const int swz  = r16 & 7;

    const uint4* gs  = wsrc + ((size_t)(b * S + ts * 128)) * 16;
    const uint4* gt0 = wtar + ((size_t)(b * T + tp * 256)) * 16;
    const uint4* gt1 = gt0 + 128 * 16;

    // stage: both panels (linear copy of pre-swizzled image), 4 iters each
    #pragma unroll
    for (int i = 0; i < 4; ++i) {
        const int idx = i * 512 + tid;
        g2l(gs + idx,  &ldsS[i * 512 + w * 64]);
        g2l(gt0 + idx, &ldsT[i * 512 + w * 64]);
    }
    __syncthreads();

    f32x4 acc[4][2];

    #pragma unroll
    for (int tile = 0; tile < 2; ++tile) {
        #pragma unroll
        for (int m = 0; m < 4; ++m)
            #pragma unroll
            for (int n = 0; n < 2; ++n)
                acc[m][n] = f32x4{0.f, 0.f, 0.f, 0.f};

        #pragma unroll
        for (int ks = 0; ks < 4; ++ks) {          // K = 4 * 32
            bf16x8 at[4], bs[2];
            #pragma unroll
            for (int m = 0; m < 4; ++m) {
                const int rl = wt * 64 + m * 16 + r16;
                at[m] = __builtin_bit_cast(bf16x8, ldsT[rl * 16 + ((ks * 4 + kg) ^ swz)]);
            }
            #pragma unroll
            for (int n = 0; n < 2; ++n) {
                const int rl = wsp * 32 + n * 16 + r16;
                bs[n] = __builtin_bit_cast(bf16x8, ldsS[rl * 16 + ((ks * 4 + kg) ^ swz)]);
            }
            #pragma unroll
            for (int m = 0; m < 4; ++m)
                #pragma unroll
                for (int n = 0; n < 2; ++n)
                    acc[m][n] = __builtin_amdgcn_mfma_f32_16x16x32_bf16(at[m], bs[n], acc[m][n], 0, 0, 0);
        }

        if (tile == 0) {
            __syncthreads();                       // all waves done reading ldsT
            #pragma unroll
            for (int i = 0; i < 4; ++i)            // prefetch next tar panel (4 loads)
                g2l(gt1 + i * 512 + tid, &ldsT[i * 512 + w * 64]);
            __builtin_amdgcn_sched_barrier(0);     // pin: loads issued before stores
        }

        // epilogue: ReLU + f32x4 stores (norms & masks folded in prep)
        const int ttc = tp * 2 + tile;
        #pragma unroll
        for (int m = 0; m < 4; ++m) {
            const int tl = wt * 64 + m * 16 + kg * 4;
            #pragma unroll
            for (int n = 0; n < 2; ++n) {
                const int sl = wsp * 32 + n * 16 + r16;
                const f32x4 a = acc[m][n];
                f32x4 o;
                o[0] = fmaxf(a[0], 0.f);
                o[1] = fmaxf(a[1], 0.f);
                o[2] = fmaxf(a[2], 0.f);
                o[3] = fmaxf(a[3], 0.f);
                float* po = out + ((size_t)(b * S + ts * 128 + sl)) * T + (size_t)ttc * 128 + tl;
                *(f32x4*)po = o;
            }
        }

        if (tile == 0) {
            // wait only the 4 stage loads (8 stores may stay in flight)
            asm volatile("s_waitcnt vmcnt(8)" ::: "memory");
            __builtin_amdgcn_s_barrier();
            __builtin_amdgcn_sched_barrier(0);
        }
    }
}

extern "C" void kernel_launch(void* const* d_in, const int* in_sizes, int n_in,
                              void* d_out, int out_size, void* d_ws, size_t ws_size,
                              hipStream_t stream) {
    const float* src    = (const float*)d_in[0];
    const float* tar    = (const float*)d_in[1];
    const int*   mask_s = (const int*)d_in[2];
    const int*   mask_t = (const int*)d_in[3];
    float*       out    = (float*)d_out;
    uint4*       ws     = (uint4*)d_ws;

    hipLaunchKernelGGL(prep, dim3(256), dim3(512), 0, stream, src, tar, mask_s, mask_t, ws);
    hipLaunchKernelGGL(gemm, dim3(1024), dim3(512), 0, stream, ws, out);
}